// Round 9
// baseline (436.892 us; speedup 1.0000x reference)
//
#include <hip/hip_runtime.h>

// SparseNeighborAttention on MI355X (gfx950)
// R9: attn_k phase-1 re-mapped: lane=(head,neighbor-slot), each lane computes a
//     full 32-dim dot with 16 fdot2 (no cross-lane reduce, no per-k selects).
//     Scores land directly in the legacy s[c] layout -> softmax/phase-2 unchanged.
//     K gathered 64B/lane via 4x dwordx4 imm-offset loads, 2-passes-ahead
//     register pipeline (3 bufs) pinned with sched_barrier(0). (256,3): no spill.
// ws layout (bytes): xb[MP*256*2] qb kb vb attb | wqkv[768*256*2] wob[256*256*2] flags[8]

typedef __bf16 bf16x8 __attribute__((ext_vector_type(8)));
typedef float f32x4 __attribute__((ext_vector_type(4)));
typedef _Float16 h2 __attribute__((ext_vector_type(2)));

#define NN 50000
#define MP 50048            // 391 * 128 (padded M)
#define MPE ((size_t)MP * 256)
#define QSCALE 0.17677669529663687f   // 1/sqrt(32)

__device__ __forceinline__ float bfl(unsigned u) { return __builtin_bit_cast(float, u << 16); }
__device__ __forceinline__ float bfh(unsigned u) { return __builtin_bit_cast(float, u & 0xFFFF0000u); }
__device__ __forceinline__ unsigned short f2bf(float f) {
    unsigned u = __builtin_bit_cast(unsigned, f);
    return (unsigned short)((u + 0x7FFFu + ((u >> 16) & 1u)) >> 16);   // RNE
}
__device__ __forceinline__ unsigned pack2(float a, float b) {
    return (unsigned)f2bf(a) | ((unsigned)f2bf(b) << 16);
}
__device__ __forceinline__ void gload16(const void* g, void* l) {
    __builtin_amdgcn_global_load_lds((const __attribute__((address_space(1))) void*)g,
                                     (__attribute__((address_space(3))) void*)l, 16, 0, 0);
}
// VALU-pipe cross-lane add/max via DPP: ctrl 0xB1=quad xor1, 0x4E=quad xor2, 0x141=row_half_mirror
template <int CTRL>
__device__ __forceinline__ float dpp_add(float x) {
    int yi = __builtin_amdgcn_update_dpp(0, __builtin_bit_cast(int, x), CTRL, 0xF, 0xF, true);
    return x + __builtin_bit_cast(float, yi);
}
template <int CTRL>
__device__ __forceinline__ float dpp_max(float x) {
    int yi = __builtin_amdgcn_update_dpp(0, __builtin_bit_cast(int, x), CTRL, 0xF, 0xF, true);
    return fmaxf(x, __builtin_bit_cast(float, yi));
}
// dot of two packed-f16 pairs (bit-cast from u32) with f32 accumulate
__device__ __forceinline__ float dot2h(unsigned a, unsigned b, float c) {
    return __builtin_amdgcn_fdot2(__builtin_bit_cast(h2, a), __builtin_bit_cast(h2, b), c, false);
}

// ---------------- prep: weights -> bf16, probe mask/idx dtype ----------------
__global__ __launch_bounds__(256) void prep_k(const float* __restrict__ Wq, const float* __restrict__ Wk,
                                              const float* __restrict__ Wv, const float* __restrict__ Wo,
                                              unsigned short* __restrict__ wqkv, unsigned short* __restrict__ wob,
                                              const void* __restrict__ idxp, const void* __restrict__ maskp,
                                              int* __restrict__ flags) {
    int t = blockIdx.x * 256 + threadIdx.x;      // grid 1024*256 = 262144 = 196608 + 65536
    if (t < 196608) {
        int j = t >> 8, i = t & 255;
        const float* W = (j < 256) ? Wq : (j < 512 ? Wk : Wv);
        wqkv[t] = f2bf(W[((size_t)(j & 255) << 8) | i]);
    } else {
        int u = t - 196608;
        wob[u] = f2bf(Wo[u]);
    }
    if (blockIdx.x == 0) {
        __shared__ int nI32, nF32, nHi;
        if (threadIdx.x == 0) { nI32 = 0; nF32 = 0; nHi = 0; }
        __syncthreads();
        const unsigned* mw = (const unsigned*)maskp;
        const unsigned* iw = (const unsigned*)idxp;
        int a = 0, b = 0, c = 0;
        for (int q = threadIdx.x; q < 1024; q += 256) {
            unsigned v = mw[q];
            if (v > 1u) a = 1;
            if (v != 0u && v != 0x3F800000u) b = 1;
            if (iw[2 * q + 1] != 0u) c = 1;
        }
        if (a) atomicOr(&nI32, 1);
        if (b) atomicOr(&nF32, 1);
        if (c) atomicOr(&nHi, 1);
        __syncthreads();
        if (threadIdx.x == 0) {
            flags[0] = (nI32 == 0) ? 1 : ((nF32 == 0) ? 2 : 0);  // 0=u8 1=i32 2=f32
            flags[1] = (nHi == 0) ? 1 : 0;                       // 1 => idx is int64
        }
    }
}

// ---------------- convx: x fp32 -> bf16, zero-pad rows to MP ----------------
__global__ __launch_bounds__(256) void convx_k(const float* __restrict__ x, unsigned short* __restrict__ xb) {
    size_t t = (size_t)blockIdx.x * 256 + threadIdx.x;  // grid 6256 -> covers MP*256/8 exactly
    size_t e = t * 8;
    uint4 o;
    if (e < (size_t)NN * 256) {
        float4 a = *(const float4*)&x[e];
        float4 b = *(const float4*)&x[e + 4];
        o.x = pack2(a.x, a.y); o.y = pack2(a.z, a.w);
        o.z = pack2(b.x, b.y); o.w = pack2(b.z, b.w);
    } else {
        o = make_uint4(0, 0, 0, 0);
    }
    *(uint4*)&xb[e] = o;
}

// ---------------- GEMM: C[M,NB] = A[M,256] @ B[NB,256]^T (both bf16, BT layout) ----------------
// MODE 0: write FP16 to qkv (3 stacked MP*256 buffers, col j -> buffer j>>8); q pre-scaled
// MODE 1: write fp32 out + bo, rows < NN only
template <int MODE>
__global__ __launch_bounds__(256)
void gemm_bt(const unsigned short* __restrict__ A, const unsigned short* __restrict__ B,
             unsigned short* __restrict__ qkv, float* __restrict__ out, const float* __restrict__ bo) {
    const int tid = threadIdx.x;
    const int wv = tid >> 6, ln = tid & 63;
    const int m0 = blockIdx.x * 128, n0 = blockIdx.y * 128;
    const int wr = wv >> 1, wc = wv & 1;
    __shared__ unsigned short As[2][128][32];
    __shared__ unsigned short Bs[2][128][32];
    f32x4 acc[4][4] = {};

    const int srow = 16 * wv + (ln >> 2);
    #define STAGE(buf, kt)                                                                     \
        {                                                                                      \
            const int col = (kt) * 32 + (ln & 3) * 8;                                          \
            _Pragma("unroll")                                                                  \
            for (int r = 0; r < 2; ++r) {                                                      \
                gload16(&A[(size_t)(m0 + 64 * r + srow) * 256 + col], &As[buf][64 * r + 16 * wv][0]); \
                gload16(&B[(size_t)(n0 + 64 * r + srow) * 256 + col], &Bs[buf][64 * r + 16 * wv][0]); \
            }                                                                                  \
        }

    STAGE(0, 0);
    const int lr = ln & 15, lk = (ln >> 4) * 8;
    for (int kt = 0; kt < 8; ++kt) {
        const int cur = kt & 1;
        __syncthreads();                 // compiler drains vmcnt before barrier -> stage(cur) complete
        if (kt < 7) STAGE(cur ^ 1, kt + 1);
        bf16x8 af[4], bfr[4];
        #pragma unroll
        for (int i = 0; i < 4; ++i) {
            af[i]  = *reinterpret_cast<const bf16x8*>(&As[cur][wr * 64 + i * 16 + lr][lk]);
            bfr[i] = *reinterpret_cast<const bf16x8*>(&Bs[cur][wc * 64 + i * 16 + lr][lk]);
        }
        #pragma unroll
        for (int mi = 0; mi < 4; ++mi)
            #pragma unroll
            for (int ni = 0; ni < 4; ++ni)
                acc[mi][ni] = __builtin_amdgcn_mfma_f32_16x16x32_bf16(af[mi], bfr[ni], acc[mi][ni], 0, 0, 0);
        __syncthreads();
    }

    const int rbase = m0 + wr * 64 + (ln >> 4) * 4;   // C/D map: col=lane&15, row=(lane>>4)*4+reg
    const int cbase = n0 + wc * 64 + (ln & 15);
    #pragma unroll
    for (int mi = 0; mi < 4; ++mi) {
        #pragma unroll
        for (int ni = 0; ni < 4; ++ni) {
            const int gn = cbase + ni * 16;
            #pragma unroll
            for (int j = 0; j < 4; ++j) {
                const int gm = rbase + mi * 16 + j;
                float v = acc[mi][ni][j];
                if (MODE == 0) {
                    const float vs = (gn < 256) ? v * QSCALE : v;   // pre-scale q rows
                    qkv[(size_t)(gn >> 8) * MPE + (size_t)gm * 256 + (gn & 255)] =
                        __builtin_bit_cast(unsigned short, (_Float16)vs);
                } else {
                    if (gm < NN) out[(size_t)gm * 256 + gn] = v + bo[gn];
                }
            }
        }
    }
    #undef STAGE
}

// ---------------- attention: one wave per node ----------------
// Phase 1: lane=(h=ln>>3, j=ln&7); pass c handles neighbor k=8c+j; lane computes the
//   full 32-dim dot itself (16 fdot2, 4 ILP chains) -> s[c] directly; no DPP reduce.
// Phase 2: lane=dim-slice (dims 4ln..4ln+3, head=ln>>3); weight broadcast via bpermute.
__global__ __launch_bounds__(256, 3) void attn_k(const unsigned short* __restrict__ qb,
                                                 const unsigned short* __restrict__ kb,
                                                 const unsigned short* __restrict__ vb,
                                                 const void* __restrict__ idxp, const void* __restrict__ maskp,
                                                 unsigned short* __restrict__ attb, const int* __restrict__ flags) {
    const int wv = threadIdx.x >> 6, ln = threadIdx.x & 63;
    const int node = blockIdx.x * 4 + wv;                 // grid 12500 * 4 = 50000 exactly
    const int mlay = flags[0], i64 = flags[1];
    const size_t eb = (size_t)node * 64 + ln;

    int idx = i64 ? ((const int*)idxp)[2 * eb] : ((const int*)idxp)[eb];   // LE low word for i64
    int padi;
    if (mlay == 1)       padi = (((const int*)maskp)[eb] != 0);
    else if (mlay == 2)  padi = (((const unsigned*)maskp)[eb] != 0u);
    else                 padi = (((const unsigned char*)maskp)[eb] != 0);
    const unsigned long long pm = __ballot(padi);         // bit k = neighbor k is PAD (wave-uniform)
    int idx_eff = padi ? node : idx;                      // PAD -> node's own row (weight will be 0)

    const int h = ln >> 3, j = ln & 7;
    const int hoff = h << 6;                              // byte offset of head segment in 512B row
    const unsigned mlo = (unsigned)pm, mhi = (unsigned)(pm >> 32);

    // ---- q: this head's 64B segment (pre-scaled f16) ----
    const char* qrow = (const char*)qb + (((size_t)node) << 9) + hoff;
    const uint4 q0 = *(const uint4*)(qrow);
    const uint4 q1 = *(const uint4*)(qrow + 16);
    const uint4 q2 = *(const uint4*)(qrow + 32);
    const uint4 q3 = *(const uint4*)(qrow + 48);

    // ---- phase 1: 8 passes, 2-ahead register pipeline (3 bufs) ----
    const char* kbase = (const char*)kb;
    uint4 kr[3][4];
    #define KISSUE(buf, c)                                                                \
        {                                                                                 \
            const int nk = __builtin_amdgcn_ds_bpermute(4 * j + 32 * (c), idx_eff);       \
            const unsigned vo = ((unsigned)nk << 9) + hoff;                               \
            kr[buf][0] = *(const uint4*)(kbase + vo);                                     \
            kr[buf][1] = *(const uint4*)(kbase + vo + 16);                                \
            kr[buf][2] = *(const uint4*)(kbase + vo + 32);                                \
            kr[buf][3] = *(const uint4*)(kbase + vo + 48);                                \
        }
    KISSUE(0, 0)
    KISSUE(1, 1)
    __builtin_amdgcn_sched_barrier(0);

    float s[8];
    #pragma unroll
    for (int c = 0; c < 8; ++c) {
        if (c < 6) { KISSUE((c + 2) % 3, c + 2) }
        __builtin_amdgcn_sched_barrier(0);
        const int cb = c % 3;
        float a0 = dot2h(q0.x, kr[cb][0].x, 0.f);
        float a1 = dot2h(q1.x, kr[cb][1].x, 0.f);
        float a2 = dot2h(q2.x, kr[cb][2].x, 0.f);
        float a3 = dot2h(q3.x, kr[cb][3].x, 0.f);
        a0 = dot2h(q0.y, kr[cb][0].y, a0); a1 = dot2h(q1.y, kr[cb][1].y, a1);
        a2 = dot2h(q2.y, kr[cb][2].y, a2); a3 = dot2h(q3.y, kr[cb][3].y, a3);
        a0 = dot2h(q0.z, kr[cb][0].z, a0); a1 = dot2h(q1.z, kr[cb][1].z, a1);
        a2 = dot2h(q2.z, kr[cb][2].z, a2); a3 = dot2h(q3.z, kr[cb][3].z, a3);
        a0 = dot2h(q0.w, kr[cb][0].w, a0); a1 = dot2h(q1.w, kr[cb][1].w, a1);
        a2 = dot2h(q2.w, kr[cb][2].w, a2); a3 = dot2h(q3.w, kr[cb][3].w, a3);
        const float dot = (a0 + a1) + (a2 + a3);
        const unsigned word = (c < 4) ? mlo : mhi;
        const unsigned bit = (word >> (((8 * c) & 31) + j)) & 1u;   // PAD bit for k=8c+j
        s[c] = bit ? -1e30f : dot;
    }
    #undef KISSUE

    // ---- issue ALL 64 V-row gathers (dim-slice layout); they fly during softmax ----
    uint2 va[64];
    #pragma unroll
    for (int k = 0; k < 64; ++k) {
        const unsigned nk = (unsigned)__builtin_amdgcn_readlane(idx_eff, k);
        va[k] = *((const uint2*)(vb + ((size_t)nk << 8)) + ln);
    }
    __builtin_amdgcn_sched_barrier(0);

    // ---- softmax over 64 neighbors (8 regs x 8 lanes of head group), DPP reduces ----
    float m = s[0];
    #pragma unroll
    for (int r = 1; r < 8; ++r) m = fmaxf(m, s[r]);
    m = dpp_max<0xB1>(m); m = dpp_max<0x4E>(m); m = dpp_max<0x141>(m);
    float w[8], sum = 0.f;
    #pragma unroll
    for (int r = 0; r < 8; ++r) { w[r] = __expf(s[r] - m); sum += w[r]; }
    sum = dpp_add<0xB1>(sum); sum = dpp_add<0x4E>(sum); sum = dpp_add<0x141>(sum);
    const float inv = (m > -1e29f && sum > 0.f) ? 1.0f / sum : 0.0f;   // all-PAD -> 0 (nan_to_num)

    // ---- phase 2: weighted V sum (f32 accumulate from f16 V), normalize at the end ----
    float o0 = 0.f, o1 = 0.f, o2 = 0.f, o3 = 0.f;
    const int baddr = (ln & 56) * 4;   // byte addr of head-group base lane for ds_bpermute
    #pragma unroll
    for (int k = 0; k < 64; ++k) {
        // weight for neighbor k lives at lane (ln&56)|(k&7), reg k>>3
        const int wi = __builtin_amdgcn_ds_bpermute(baddr + 4 * (k & 7),
                                                    __builtin_bit_cast(int, w[k >> 3]));
        const float wk = __builtin_bit_cast(float, wi);
        const h2 vx = __builtin_bit_cast(h2, va[k].x);
        const h2 vy = __builtin_bit_cast(h2, va[k].y);
        o0 += wk * (float)vx.x; o1 += wk * (float)vx.y;
        o2 += wk * (float)vy.x; o3 += wk * (float)vy.y;
    }
    uint2 ov;
    ov.x = pack2(o0 * inv, o1 * inv);
    ov.y = pack2(o2 * inv, o3 * inv);
    *(uint2*)&attb[(size_t)node * 256 + ln * 4] = ov;
}

// ---------------- launch ----------------
extern "C" void kernel_launch(void* const* d_in, const int* in_sizes, int n_in,
                              void* d_out, int out_size, void* d_ws, size_t ws_size,
                              hipStream_t stream) {
    const float* x   = (const float*)d_in[0];
    const void*  idx = d_in[1];
    const void*  msk = d_in[2];
    const float* Wq  = (const float*)d_in[3];
    const float* Wk  = (const float*)d_in[4];
    const float* Wv  = (const float*)d_in[5];
    const float* Wo  = (const float*)d_in[6];
    const float* bo  = (const float*)d_in[7];
    float* out = (float*)d_out;

    unsigned short* xb   = (unsigned short*)d_ws;
    unsigned short* qb   = xb + MPE;
    unsigned short* kb   = qb + MPE;
    unsigned short* vb   = kb + MPE;
    unsigned short* attb = vb + MPE;
    unsigned short* wqkv = attb + MPE;
    unsigned short* wob  = wqkv + 768 * 256;
    int* flags = (int*)(wob + 256 * 256);

    prep_k<<<1024, 256, 0, stream>>>(Wq, Wk, Wv, Wo, wqkv, wob, idx, msk, flags);
    convx_k<<<6256, 256, 0, stream>>>(x, xb);
    gemm_bt<0><<<dim3(391, 6), 256, 0, stream>>>(xb, wqkv, qb, nullptr, nullptr);
    attn_k<<<12500, 256, 0, stream>>>(qb, kb, vb, idx, msk, attb, flags);
    gemm_bt<1><<<dim3(391, 2), 256, 0, stream>>>(attb, wob, nullptr, out, bo);
}

// Round 11
// 417.630 us; speedup vs baseline: 1.0461x; 1.0461x over previous
//
#include <hip/hip_runtime.h>

// SparseNeighborAttention on MI355X (gfx950)
// R11 == R10 (resubmit after GPU acquisition timeout):
//      attn_k = R8 verbatim (best measured, 234us; R9's remap reverted).
//      GEMMs: BK=64 (4 K-steps, half the barriers), st-style XOR swizzle
//      (linear LDS dest + pre-swizzled global src + swizzled ds_read, G21),
//      XCD-bijective block remap (m204) with A-panel-major order.
//      All GEMM changes are data-movement permutations -> bit-identical output.
// ws layout (bytes): xb[MP*256*2] qb kb vb attb | wqkv[768*256*2] wob[256*256*2] flags[8]

typedef __bf16 bf16x8 __attribute__((ext_vector_type(8)));
typedef float f32x4 __attribute__((ext_vector_type(4)));
typedef _Float16 h2 __attribute__((ext_vector_type(2)));

#define NN 50000
#define MP 50048            // 391 * 128 (padded M)
#define MPE ((size_t)MP * 256)
#define QSCALE 0.17677669529663687f   // 1/sqrt(32)

__device__ __forceinline__ float bfl(unsigned u) { return __builtin_bit_cast(float, u << 16); }
__device__ __forceinline__ float bfh(unsigned u) { return __builtin_bit_cast(float, u & 0xFFFF0000u); }
__device__ __forceinline__ unsigned short f2bf(float f) {
    unsigned u = __builtin_bit_cast(unsigned, f);
    return (unsigned short)((u + 0x7FFFu + ((u >> 16) & 1u)) >> 16);   // RNE
}
__device__ __forceinline__ unsigned pack2(float a, float b) {
    return (unsigned)f2bf(a) | ((unsigned)f2bf(b) << 16);
}
__device__ __forceinline__ void gload16(const void* g, void* l) {
    __builtin_amdgcn_global_load_lds((const __attribute__((address_space(1))) void*)g,
                                     (__attribute__((address_space(3))) void*)l, 16, 0, 0);
}
// VALU-pipe cross-lane add/max via DPP: ctrl 0xB1=quad xor1, 0x4E=quad xor2, 0x141=row_half_mirror
template <int CTRL>
__device__ __forceinline__ float dpp_add(float x) {
    int yi = __builtin_amdgcn_update_dpp(0, __builtin_bit_cast(int, x), CTRL, 0xF, 0xF, true);
    return x + __builtin_bit_cast(float, yi);
}
template <int CTRL>
__device__ __forceinline__ float dpp_max(float x) {
    int yi = __builtin_amdgcn_update_dpp(0, __builtin_bit_cast(int, x), CTRL, 0xF, 0xF, true);
    return fmaxf(x, __builtin_bit_cast(float, yi));
}
// dot of two packed-f16 pairs (bit-cast from u32) with f32 accumulate
__device__ __forceinline__ float dot2h(unsigned a, unsigned b, float c) {
    return __builtin_amdgcn_fdot2(__builtin_bit_cast(h2, a), __builtin_bit_cast(h2, b), c, false);
}

// ---------------- prep: weights -> bf16, probe mask/idx dtype ----------------
__global__ __launch_bounds__(256) void prep_k(const float* __restrict__ Wq, const float* __restrict__ Wk,
                                              const float* __restrict__ Wv, const float* __restrict__ Wo,
                                              unsigned short* __restrict__ wqkv, unsigned short* __restrict__ wob,
                                              const void* __restrict__ idxp, const void* __restrict__ maskp,
                                              int* __restrict__ flags) {
    int t = blockIdx.x * 256 + threadIdx.x;      // grid 1024*256 = 262144 = 196608 + 65536
    if (t < 196608) {
        int j = t >> 8, i = t & 255;
        const float* W = (j < 256) ? Wq : (j < 512 ? Wk : Wv);
        wqkv[t] = f2bf(W[((size_t)(j & 255) << 8) | i]);
    } else {
        int u = t - 196608;
        wob[u] = f2bf(Wo[u]);
    }
    if (blockIdx.x == 0) {
        __shared__ int nI32, nF32, nHi;
        if (threadIdx.x == 0) { nI32 = 0; nF32 = 0; nHi = 0; }
        __syncthreads();
        const unsigned* mw = (const unsigned*)maskp;
        const unsigned* iw = (const unsigned*)idxp;
        int a = 0, b = 0, c = 0;
        for (int q = threadIdx.x; q < 1024; q += 256) {
            unsigned v = mw[q];
            if (v > 1u) a = 1;
            if (v != 0u && v != 0x3F800000u) b = 1;
            if (iw[2 * q + 1] != 0u) c = 1;
        }
        if (a) atomicOr(&nI32, 1);
        if (b) atomicOr(&nF32, 1);
        if (c) atomicOr(&nHi, 1);
        __syncthreads();
        if (threadIdx.x == 0) {
            flags[0] = (nI32 == 0) ? 1 : ((nF32 == 0) ? 2 : 0);  // 0=u8 1=i32 2=f32
            flags[1] = (nHi == 0) ? 1 : 0;                       // 1 => idx is int64
        }
    }
}

// ---------------- convx: x fp32 -> bf16, zero-pad rows to MP ----------------
__global__ __launch_bounds__(256) void convx_k(const float* __restrict__ x, unsigned short* __restrict__ xb) {
    size_t t = (size_t)blockIdx.x * 256 + threadIdx.x;  // grid 6256 -> covers MP*256/8 exactly
    size_t e = t * 8;
    uint4 o;
    if (e < (size_t)NN * 256) {
        float4 a = *(const float4*)&x[e];
        float4 b = *(const float4*)&x[e + 4];
        o.x = pack2(a.x, a.y); o.y = pack2(a.z, a.w);
        o.z = pack2(b.x, b.y); o.w = pack2(b.z, b.w);
    } else {
        o = make_uint4(0, 0, 0, 0);
    }
    *(uint4*)&xb[e] = o;
}

// ---------------- GEMM: C[M,NB] = A[M,256] @ B[NB,256]^T (both bf16, BT layout) ----------------
// BK=64, XOR-swizzled LDS (G21: linear gload_lds dest + pre-swizzled global col +
// swizzled ds_read; involution byte ^= (row&7)<<4). 1D grid, XCD-bijective remap
// (m204), A-panel-major: runs of NY consecutive wgids share the A panel.
// MODE 0: write FP16 qkv (q pre-scaled). MODE 1: fp32 out + bo, rows < NN.
template <int MODE, int NY, int NWG>
__global__ __launch_bounds__(256)
void gemm_bt(const unsigned short* __restrict__ A, const unsigned short* __restrict__ B,
             unsigned short* __restrict__ qkv, float* __restrict__ out, const float* __restrict__ bo) {
    // --- XCD-bijective chunk remap (m204) ---
    constexpr int Q = NWG / 8, R = NWG % 8;
    const int f = blockIdx.x;
    const int xcd = f & 7, pos = f >> 3;
    const int wgid = (xcd < R ? xcd * (Q + 1) : R * (Q + 1) + (xcd - R) * Q) + pos;
    const int m0 = (wgid / NY) * 128, n0 = (wgid % NY) * 128;

    const int tid = threadIdx.x;
    const int wv = tid >> 6, ln = tid & 63;
    const int wr = wv >> 1, wc = wv & 1;
    __shared__ unsigned short As[2][128][64];
    __shared__ unsigned short Bs[2][128][64];
    f32x4 acc[4][4] = {};

    // Staging: lane covers row 32r+8wv+(ln>>3), source col swizzled so that the
    // linear LDS dest (byte (ln&7)*16 of the row) holds G[row][cb ^ (row&7)<<4].
    const int srow = 8 * wv + (ln >> 3);
    const int scolE = (((ln & 7) ^ (ln >> 3)) << 3);      // swizzled source col (elements)
    #define STAGE(buf, kt)                                                                      \
        {                                                                                       \
            _Pragma("unroll")                                                                   \
            for (int r = 0; r < 4; ++r) {                                                       \
                gload16(&A[(size_t)(m0 + 32 * r + srow) * 256 + (kt) * 64 + scolE],             \
                        &As[buf][32 * r + 8 * wv][0]);                                          \
                gload16(&B[(size_t)(n0 + 32 * r + srow) * 256 + (kt) * 64 + scolE],             \
                        &Bs[buf][32 * r + 8 * wv][0]);                                          \
            }                                                                                   \
        }

    STAGE(0, 0);
    const int lr = ln & 15;
    const int lkb = (ln >> 4) * 16;              // linear read col (bytes) within 32-k block
    const int swz = (ln & 7) << 4;               // read-side involution (row&7 == ln&7)
    for (int kt = 0; kt < 4; ++kt) {
        const int cur = kt & 1;
        __syncthreads();                 // compiler drains vmcnt before barrier -> stage(cur) complete
        if (kt < 3) STAGE(cur ^ 1, kt + 1);
        #pragma unroll
        for (int k2 = 0; k2 < 2; ++k2) {
            bf16x8 af[4], bfr[4];
            #pragma unroll
            for (int i = 0; i < 4; ++i) {
                af[i]  = *reinterpret_cast<const bf16x8*>(
                    (const char*)&As[cur][wr * 64 + i * 16 + lr][0] + ((k2 * 64 + lkb) ^ swz));
                bfr[i] = *reinterpret_cast<const bf16x8*>(
                    (const char*)&Bs[cur][wc * 64 + i * 16 + lr][0] + ((k2 * 64 + lkb) ^ swz));
            }
            #pragma unroll
            for (int mi = 0; mi < 4; ++mi)
                #pragma unroll
                for (int ni = 0; ni < 4; ++ni)
                    acc[mi][ni] = __builtin_amdgcn_mfma_f32_16x16x32_bf16(af[mi], bfr[ni], acc[mi][ni], 0, 0, 0);
        }
        __syncthreads();
    }

    const int rbase = m0 + wr * 64 + (ln >> 4) * 4;   // C/D map: col=lane&15, row=(lane>>4)*4+reg
    const int cbase = n0 + wc * 64 + (ln & 15);
    #pragma unroll
    for (int mi = 0; mi < 4; ++mi) {
        #pragma unroll
        for (int ni = 0; ni < 4; ++ni) {
            const int gn = cbase + ni * 16;
            #pragma unroll
            for (int j = 0; j < 4; ++j) {
                const int gm = rbase + mi * 16 + j;
                float v = acc[mi][ni][j];
                if (MODE == 0) {
                    const float vs = (gn < 256) ? v * QSCALE : v;   // pre-scale q rows
                    qkv[(size_t)(gn >> 8) * MPE + (size_t)gm * 256 + (gn & 255)] =
                        __builtin_bit_cast(unsigned short, (_Float16)vs);
                } else {
                    if (gm < NN) out[(size_t)gm * 256 + gn] = v + bo[gn];
                }
            }
        }
    }
    #undef STAGE
}

// ---------------- attention: one wave per node (R8 verbatim) ----------------
// Lane layout: lane ln owns dims 4*ln..4*ln+3 of the 256-dim row; head = ln>>3, pos p = ln&7.
// f16 K/V + fdot2 scores; PAD->own-row redirect; batched gathers; (256,3) = no spill.
__global__ __launch_bounds__(256, 3) void attn_k(const unsigned short* __restrict__ qb,
                                                 const unsigned short* __restrict__ kb,
                                                 const unsigned short* __restrict__ vb,
                                                 const void* __restrict__ idxp, const void* __restrict__ maskp,
                                                 unsigned short* __restrict__ attb, const int* __restrict__ flags) {
    const int wv = threadIdx.x >> 6, ln = threadIdx.x & 63;
    const int node = blockIdx.x * 4 + wv;                 // grid 12500 * 4 = 50000 exactly
    const int mlay = flags[0], i64 = flags[1];
    const size_t eb = (size_t)node * 64 + ln;

    int idx = i64 ? ((const int*)idxp)[2 * eb] : ((const int*)idxp)[eb];   // LE low word for i64
    int padi;
    if (mlay == 1)       padi = (((const int*)maskp)[eb] != 0);
    else if (mlay == 2)  padi = (((const unsigned*)maskp)[eb] != 0u);
    else                 padi = (((const unsigned char*)maskp)[eb] != 0);
    const unsigned long long pm = __ballot(padi);         // bit k = neighbor k is PAD (wave-uniform)
    const int idx_eff = padi ? node : idx;                // PAD -> node's own row (weight will be 0)

    const uint2 qv = *(const uint2*)&qb[(size_t)node * 256 + ln * 4];   // q pre-scaled, packed f16

    const int p = ln & 7;

    // ---- issue ALL 64 K-row gathers (SGPR row base + shared lane offset) ----
    uint2 ka[64];
    #pragma unroll
    for (int k = 0; k < 64; ++k) {
        const unsigned nk = (unsigned)__builtin_amdgcn_readlane(idx_eff, k);
        ka[k] = *((const uint2*)(kb + ((size_t)nk << 8)) + ln);
    }
    __builtin_amdgcn_sched_barrier(0);    // loads stay batched above the compute

    float s[8];
    #pragma unroll
    for (int k = 0; k < 64; ++k) {
        const uint2 kv = ka[k];
        float part = dot2h(qv.x, kv.x, dot2h(qv.y, kv.y, 0.0f));   // 2 VOP3P dots
        part = dpp_add<0xB1>(part);    // quad xor1
        part = dpp_add<0x4E>(part);    // quad xor2
        part = dpp_add<0x141>(part);   // row_half_mirror joins the two quads of the 8-group
        const float sc = ((pm >> k) & 1ull) ? -1e30f : part;       // scale pre-applied to q
        if ((k & 7) == p) s[k >> 3] = sc;    // k compile-time -> static index
    }

    // ---- issue ALL 64 V-row gathers; they fly during the softmax ----
    uint2 va[64];
    #pragma unroll
    for (int k = 0; k < 64; ++k) {
        const unsigned nk = (unsigned)__builtin_amdgcn_readlane(idx_eff, k);
        va[k] = *((const uint2*)(vb + ((size_t)nk << 8)) + ln);
    }
    __builtin_amdgcn_sched_barrier(0);

    // ---- softmax over 64 neighbors (8 regs x 8 lanes of head group), DPP reduces ----
    float m = s[0];
    #pragma unroll
    for (int r = 1; r < 8; ++r) m = fmaxf(m, s[r]);
    m = dpp_max<0xB1>(m); m = dpp_max<0x4E>(m); m = dpp_max<0x141>(m);
    float w[8], sum = 0.f;
    #pragma unroll
    for (int r = 0; r < 8; ++r) { w[r] = __expf(s[r] - m); sum += w[r]; }
    sum = dpp_add<0xB1>(sum); sum = dpp_add<0x4E>(sum); sum = dpp_add<0x141>(sum);
    const float inv = (m > -1e29f && sum > 0.f) ? 1.0f / sum : 0.0f;   // all-PAD -> 0 (nan_to_num)
    #pragma unroll
    for (int r = 0; r < 8; ++r) w[r] *= inv;

    // ---- phase 2: weighted V sum (f32 accumulate from f16 V) ----
    float o0 = 0.f, o1 = 0.f, o2 = 0.f, o3 = 0.f;
    const int baddr = (ln & 56) * 4;   // byte addr of head-group base lane for ds_bpermute
    #pragma unroll
    for (int k = 0; k < 64; ++k) {
        // weight for neighbor k lives at lane (ln&56)|(k&7), reg k>>3
        const int wi = __builtin_amdgcn_ds_bpermute(baddr + 4 * (k & 7),
                                                    __builtin_bit_cast(int, w[k >> 3]));
        const float wk = __builtin_bit_cast(float, wi);
        const h2 vx = __builtin_bit_cast(h2, va[k].x);
        const h2 vy = __builtin_bit_cast(h2, va[k].y);
        o0 += wk * (float)vx.x; o1 += wk * (float)vx.y;
        o2 += wk * (float)vy.x; o3 += wk * (float)vy.y;
    }
    uint2 ov;
    ov.x = pack2(o0, o1);
    ov.y = pack2(o2, o3);
    *(uint2*)&attb[(size_t)node * 256 + ln * 4] = ov;
}

// ---------------- launch ----------------
extern "C" void kernel_launch(void* const* d_in, const int* in_sizes, int n_in,
                              void* d_out, int out_size, void* d_ws, size_t ws_size,
                              hipStream_t stream) {
    const float* x   = (const float*)d_in[0];
    const void*  idx = d_in[1];
    const void*  msk = d_in[2];
    const float* Wq  = (const float*)d_in[3];
    const float* Wk  = (const float*)d_in[4];
    const float* Wv  = (const float*)d_in[5];
    const float* Wo  = (const float*)d_in[6];
    const float* bo  = (const float*)d_in[7];
    float* out = (float*)d_out;

    unsigned short* xb   = (unsigned short*)d_ws;
    unsigned short* qb   = xb + MPE;
    unsigned short* kb   = qb + MPE;
    unsigned short* vb   = kb + MPE;
    unsigned short* attb = vb + MPE;
    unsigned short* wqkv = attb + MPE;
    unsigned short* wob  = wqkv + 768 * 256;
    int* flags = (int*)(wob + 256 * 256);

    prep_k<<<1024, 256, 0, stream>>>(Wq, Wk, Wv, Wo, wqkv, wob, idx, msk, flags);
    convx_k<<<6256, 256, 0, stream>>>(x, xb);
    gemm_bt<0, 6, 2346><<<2346, 256, 0, stream>>>(xb, wqkv, qb, nullptr, nullptr);
    attn_k<<<12500, 256, 0, stream>>>(qb, kb, vb, idx, msk, attb, flags);
    gemm_bt<1, 2, 782><<<782, 256, 0, stream>>>(attb, wob, nullptr, out, bo);
}